// Round 16
// baseline (246.698 us; speedup 1.0000x reference)
//
#include <hip/hip_runtime.h>
#include <hip/hip_bf16.h>

// CoarseGraining: y[i,b] = heg[b] * sum_j exp(-beta[j,b] * d2(i,j)) * wrho[j]
// N = M = 8192, NB = 16, WIDTH = 32. Inputs float32, output float32.
// R13 (2 i/wave, packed f32, hw v_exp, 1024 blocks): pairs 134us, total 190.6.
// R14 (poly exp) and R15 (j-split TLP) both regressed -> pairs is within ~25%
// of its exp-issue floor (~79us at ~11.6cyc/wave-exp); the remaining lever is
// the ~56us OUTSIDE pairs (prep + dispatch gaps, constant across R10-R15).
// R16: ONE persistent kernel. Blocks 0..31 prep; device-scope flag sync
// (all 1024 blocks co-resident by __launch_bounds__(256,4) guarantee);
// then R13's pairs loop. Flag zeroed by a 4-byte memset node (ws is 0xAA).
// Builtins: exp2 = __builtin_amdgcn_exp2f, log2 = __builtin_amdgcn_logf.

#define N_PTS 8192
#define M_PTS 8192
#define NBASIS 16
#define WIDTH 32
#define PREP_BLOCKS 32

typedef float v2f __attribute__((ext_vector_type(2)));

__device__ __forceinline__ float exp2_hw(float x) { return __builtin_amdgcn_exp2f(x); }
__device__ __forceinline__ float log2_hw(float x) { return __builtin_amdgcn_logf(x); }

__device__ __forceinline__ float fast_tanh(float z) {
    float a = fabsf(z);
    float t = __expf(-2.0f * a);
    float r = (1.0f - t) / (1.0f + t);
    return copysignf(r, z);
}

__device__ __forceinline__ float log_cosh_f(float x) {
    float a = fabsf(x);
    return a + __logf(1.0f + __expf(-2.0f * a)) - 0.6931471805599453f;
}

// ---------------- Fused kernel ----------------
// Phase 1 (blocks 0..31): per-source prep -> cw, bnq, hegf; fence; flag++.
// Phase 2 (all 1024 blocks): spin on flag==32, then all-pairs (R13 form).
__global__ __launch_bounds__(256, 4)
void cg_all(const float* __restrict__ rho,
            const float* __restrict__ gamma,
            const float* __restrict__ coords,
            const float* __restrict__ weights,
            const float* __restrict__ oc,
            const float* __restrict__ w1,
            const float* __restrict__ b1,
            const float* __restrict__ w2,
            const float* __restrict__ b2,
            float4* __restrict__ cw,
            float4* __restrict__ bnq,
            float* __restrict__ hegf,
            int* __restrict__ flag,
            float* __restrict__ out)
{
    const float PI_F = 3.14159265358979323846f;
    const float LOG2E = 1.4426950408889634f;
    int t = threadIdx.x;

    // ---------- Phase 1: prep (blocks 0..31 only) ----------
    if (blockIdx.x < PREP_BLOCKS) {
        __shared__ float s_w1[WIDTH], s_b1[WIDTH], s_w2[WIDTH * NBASIS], s_b2[NBASIS];
        if (t < WIDTH) { s_w1[t] = w1[t]; s_b1[t] = b1[t]; }
        if (t < NBASIS) s_b2[t] = b2[t];
        s_w2[t] = w2[t];
        s_w2[t + 256] = w2[t + 256];
        __syncthreads();

        int j = blockIdx.x * 256 + t;
        {
            float r = rho[j];
            float g = gamma[j];
            const float c83 = 38.28312007948569f;              // 4*(3*pi^2)^(2/3)
            float r83 = exp2_hw(2.6666666667f * log2_hw(r));   // r^(8/3)
            float s2 = g / (c83 * r83);
            float x = __logf(s2 + 1e-4f);

            float emb[NBASIS];
            #pragma unroll
            for (int b = 0; b < NBASIS; ++b) emb[b] = s_b2[b];
            #pragma unroll 4
            for (int w = 0; w < WIDTH; ++w) {
                float h = fast_tanh(fmaf(x, s_w1[w], s_b1[w]));
                #pragma unroll
                for (int b = 0; b < NBASIS; ++b)
                    emb[b] = fmaf(h, s_w2[w * NBASIS + b], emb[b]);
            }
            float pref = PI_F * exp2_hw(0.6666666667f * log2_hw(0.5f * r));
            float scale = -LOG2E * pref;
            #pragma unroll
            for (int q = 0; q < 4; ++q) {
                bnq[q * N_PTS + j] = make_float4(scale * log_cosh_f(emb[4 * q + 0]),
                                                 scale * log_cosh_f(emb[4 * q + 1]),
                                                 scale * log_cosh_f(emb[4 * q + 2]),
                                                 scale * log_cosh_f(emb[4 * q + 3]));
            }
            cw[j] = make_float4(coords[j * 3 + 0],
                                coords[j * 3 + 1],
                                coords[j * 3 + 2],
                                weights[j] * r);
        }

        if (blockIdx.x == 0 && t == 0) {
            float emb0[NBASIS];
            #pragma unroll
            for (int b = 0; b < NBASIS; ++b) emb0[b] = s_b2[b];
            for (int w = 0; w < WIDTH; ++w) {
                float h = fast_tanh(s_b1[w]);   // x = 0
                #pragma unroll
                for (int b = 0; b < NBASIS; ++b)
                    emb0[b] = fmaf(h, s_w2[w * NBASIS + b], emb0[b]);
            }
            #pragma unroll
            for (int b = 0; b < NBASIS; ++b) {
                float lc = fmaxf(log_cosh_f(emb0[b]), 0.0f);
                hegf[b] = lc * sqrtf(lc);       // lc^1.5
            }
        }

        __threadfence();       // release this thread's ws stores to device scope
        __syncthreads();
        if (t == 0)
            __hip_atomic_fetch_add(flag, 1, __ATOMIC_RELEASE,
                                   __HIP_MEMORY_SCOPE_AGENT);
    }

    // ---------- Grid-wide sync: wait for all 32 prep blocks ----------
    if (t == 0) {
        while (__hip_atomic_load(flag, __ATOMIC_ACQUIRE,
                                 __HIP_MEMORY_SCOPE_AGENT) < PREP_BLOCKS)
            __builtin_amdgcn_s_sleep(8);
    }
    __syncthreads();

    // ---------- Phase 2: all-pairs (R13 structure) ----------
    int wave = (blockIdx.x << 2) | (t >> 6);
    int lane = t & 63;
    int i0 = wave << 1;
    int i1 = i0 | 1;

    v2f oxv = { oc[i0 * 3 + 0], oc[i1 * 3 + 0] };
    v2f oyv = { oc[i0 * 3 + 1], oc[i1 * 3 + 1] };
    v2f ozv = { oc[i0 * 3 + 2], oc[i1 * 3 + 2] };

    v2f acc[NBASIS];
    #pragma unroll
    for (int b = 0; b < NBASIS; ++b) acc[b] = (v2f)0.0f;

    #pragma unroll 2
    for (int k = 0; k < N_PTS / 64; ++k) {
        int j = (k << 6) | lane;                 // lane-consecutive: coalesced
        float4 c = cw[j];
        v2f dx = oxv - c.x;
        v2f dy = oyv - c.y;
        v2f dz = ozv - c.z;
        v2f d2 = dx * dx + dy * dy + dz * dz;    // pk_mul + 2x pk_fma
        #pragma unroll
        for (int q = 0; q < 4; ++q) {
            float4 b4 = bnq[q * N_PTS + j];      // coalesced dwordx4
            v2f p0 = b4.x * d2;                  // pk_mul
            v2f p1 = b4.y * d2;
            v2f p2 = b4.z * d2;
            v2f p3 = b4.w * d2;
            v2f e0 = { exp2_hw(p0.x), exp2_hw(p0.y) };
            v2f e1 = { exp2_hw(p1.x), exp2_hw(p1.y) };
            v2f e2 = { exp2_hw(p2.x), exp2_hw(p2.y) };
            v2f e3 = { exp2_hw(p3.x), exp2_hw(p3.y) };
            acc[q * 4 + 0] += e0 * c.w;          // pk_fma
            acc[q * 4 + 1] += e1 * c.w;
            acc[q * 4 + 2] += e2 * c.w;
            acc[q * 4 + 3] += e3 * c.w;
        }
    }

    // 6-step butterfly over 64 lanes, 16 v2f values
    #pragma unroll
    for (int m = 1; m < 64; m <<= 1) {
        #pragma unroll
        for (int b = 0; b < NBASIS; ++b) {
            v2f other = { __shfl_xor(acc[b].x, m, 64),
                          __shfl_xor(acc[b].y, m, 64) };
            acc[b] += other;
        }
    }

    if (lane == 0) {
        #pragma unroll
        for (int b = 0; b < NBASIS; ++b) {
            float h = hegf[b];                   // wave-uniform s_load
            out[i0 * NBASIS + b] = acc[b].x * h;
            out[i1 * NBASIS + b] = acc[b].y * h;
        }
    }
}

extern "C" void kernel_launch(void* const* d_in, const int* in_sizes, int n_in,
                              void* d_out, int out_size, void* d_ws, size_t ws_size,
                              hipStream_t stream) {
    const float* rho        = (const float*)d_in[0];
    const float* gamma      = (const float*)d_in[1];
    const float* coords     = (const float*)d_in[2];
    const float* weights    = (const float*)d_in[3];
    const float* out_coords = (const float*)d_in[4];
    const float* w1         = (const float*)d_in[5];
    const float* b1         = (const float*)d_in[6];
    const float* w2         = (const float*)d_in[7];
    const float* b2         = (const float*)d_in[8];

    char* ws = (char*)d_ws;
    // ws layout (~640.5 KiB — well under proven 1.1253 MB budget):
    //   cw   : N * float4              = 128 KiB  @ 0
    //   bnq  : 4 planes * N * float4   = 512 KiB  @ 128K
    //   hegf : 16 * float (64 B)                  @ 640K
    //   flag : 1 int                              @ 640K + 256
    float4* cw   = (float4*)(ws);
    float4* bnq  = (float4*)(ws + (128 << 10));
    float*  hegf = (float*) (ws + (640 << 10));
    int*    flag = (int*)   (ws + (640 << 10) + 256);

    // ws is re-poisoned to 0xAA before every launch: flag MUST be zeroed.
    (void)hipMemsetAsync(flag, 0, sizeof(int), stream);

    cg_all<<<M_PTS / 8, 256, 0, stream>>>(rho, gamma, coords, weights,
                                          out_coords, w1, b1, w2, b2,
                                          cw, bnq, hegf, flag,
                                          (float*)d_out);
}

// Round 17
// 211.546 us; speedup vs baseline: 1.1662x; 1.1662x over previous
//
#include <hip/hip_runtime.h>
#include <hip/hip_bf16.h>

// CoarseGraining: y[i,b] = heg[b] * sum_j exp(-beta[j,b] * d2(i,j)) * wrho[j]
// N = M = 8192, NB = 16, WIDTH = 32. Inputs float32, output float32.
// R13 (2 i/wave, packed f32, hw v_exp): pairs 134us busy 104.5 (issue floor
// ~75us: 32x v_exp@8cyc + ~45 pk-VALU@2cyc per iter; ~30us load stalls at
// 4 waves/SIMD). R14 poly / R15 TLP / R16 fusion all regressed.
// Harness fixed overhead ~40us (R16 evidence); prep ~16us.
// R17 = R13 + k-loop unroll 4 (more loads in flight -> shrink stall slack).
// Builtins: exp2 = __builtin_amdgcn_exp2f, log2 = __builtin_amdgcn_logf.

#define N_PTS 8192
#define M_PTS 8192
#define NBASIS 16
#define WIDTH 32

typedef float v2f __attribute__((ext_vector_type(2)));

__device__ __forceinline__ float exp2_hw(float x) { return __builtin_amdgcn_exp2f(x); }
__device__ __forceinline__ float log2_hw(float x) { return __builtin_amdgcn_logf(x); }

__device__ __forceinline__ float fast_tanh(float z) {
    float a = fabsf(z);
    float t = __expf(-2.0f * a);
    float r = (1.0f - t) / (1.0f + t);
    return copysignf(r, z);
}

__device__ __forceinline__ float log_cosh_f(float x) {
    float a = fabsf(x);
    return a + __logf(1.0f + __expf(-2.0f * a)) - 0.6931471805599453f;
}

// ---------------- Stage 1: per-source-point quantities ----------------
// cw[j]        = (cx, cy, cz, wrho)
// bnq[q*N + j] = float4{ bn[j][4q..4q+3] }, bn = -log2(e)*beta (q-plane layout)
// hegf[0..15]  = log_cosh(embed(0))^1.5
__global__ __launch_bounds__(64)
void cg_prep(const float* __restrict__ rho,
             const float* __restrict__ gamma,
             const float* __restrict__ coords,
             const float* __restrict__ weights,
             const float* __restrict__ w1,
             const float* __restrict__ b1,
             const float* __restrict__ w2,
             const float* __restrict__ b2,
             float4* __restrict__ cw,
             float4* __restrict__ bnq,
             float* __restrict__ hegf)
{
    const float PI_F = 3.14159265358979323846f;
    const float LOG2E = 1.4426950408889634f;

    __shared__ float s_w1[WIDTH], s_b1[WIDTH], s_w2[WIDTH * NBASIS], s_b2[NBASIS];
    int t = threadIdx.x;
    if (t < WIDTH) { s_w1[t] = w1[t]; s_b1[t] = b1[t]; }
    if (t < NBASIS) s_b2[t] = b2[t];
    #pragma unroll
    for (int k = 0; k < 8; ++k) s_w2[t + 64 * k] = w2[t + 64 * k];
    __syncthreads();

    int j = blockIdx.x * 64 + t;
    {
        float r = rho[j];
        float g = gamma[j];
        const float c83 = 38.28312007948569f;              // 4*(3*pi^2)^(2/3)
        float r83 = exp2_hw(2.6666666667f * log2_hw(r));   // r^(8/3)
        float s2 = g / (c83 * r83);
        float x = __logf(s2 + 1e-4f);

        float emb[NBASIS];
        #pragma unroll
        for (int b = 0; b < NBASIS; ++b) emb[b] = s_b2[b];
        #pragma unroll 4
        for (int w = 0; w < WIDTH; ++w) {
            float h = fast_tanh(fmaf(x, s_w1[w], s_b1[w]));
            #pragma unroll
            for (int b = 0; b < NBASIS; ++b)
                emb[b] = fmaf(h, s_w2[w * NBASIS + b], emb[b]);
        }
        float pref = PI_F * exp2_hw(0.6666666667f * log2_hw(0.5f * r));
        float scale = -LOG2E * pref;
        #pragma unroll
        for (int q = 0; q < 4; ++q) {
            bnq[q * N_PTS + j] = make_float4(scale * log_cosh_f(emb[4 * q + 0]),
                                             scale * log_cosh_f(emb[4 * q + 1]),
                                             scale * log_cosh_f(emb[4 * q + 2]),
                                             scale * log_cosh_f(emb[4 * q + 3]));
        }

        cw[j] = make_float4(coords[j * 3 + 0],
                            coords[j * 3 + 1],
                            coords[j * 3 + 2],
                            weights[j] * r);
    }

    if (blockIdx.x == 0 && t == 0) {
        float emb0[NBASIS];
        #pragma unroll
        for (int b = 0; b < NBASIS; ++b) emb0[b] = s_b2[b];
        for (int w = 0; w < WIDTH; ++w) {
            float h = fast_tanh(s_b1[w]);   // x = 0
            #pragma unroll
            for (int b = 0; b < NBASIS; ++b)
                emb0[b] = fmaf(h, s_w2[w * NBASIS + b], emb0[b]);
        }
        #pragma unroll
        for (int b = 0; b < NBASIS; ++b) {
            float lc = fmaxf(log_cosh_f(emb0[b]), 0.0f);
            hegf[b] = lc * sqrtf(lc);       // lc^1.5
        }
    }
}

// ---------------- Stage 2: all-pairs, 2 i's/wave, float2-packed ----------
// wave w owns i0=2w, i1=2w+1; lane L handles j = 64k+L. All per-i-duplicated
// math is v2f -> v_pk_mul/fma_f32. k-loop unroll 4 keeps ~20 loads in flight
// to hide L1/L2 latency behind the exp stream. 1024 blocks x 4 waves.
__global__ __launch_bounds__(256, 4)
void cg_pairs(const float* __restrict__ oc,
              const float4* __restrict__ cw,
              const float4* __restrict__ bnq,
              const float* __restrict__ hegf,
              float* __restrict__ out)
{
    int wave = (blockIdx.x << 2) | (threadIdx.x >> 6);
    int lane = threadIdx.x & 63;
    int i0 = wave << 1;
    int i1 = i0 | 1;

    v2f oxv = { oc[i0 * 3 + 0], oc[i1 * 3 + 0] };
    v2f oyv = { oc[i0 * 3 + 1], oc[i1 * 3 + 1] };
    v2f ozv = { oc[i0 * 3 + 2], oc[i1 * 3 + 2] };

    v2f acc[NBASIS];
    #pragma unroll
    for (int b = 0; b < NBASIS; ++b) acc[b] = (v2f)0.0f;

    #pragma unroll 4
    for (int k = 0; k < N_PTS / 64; ++k) {
        int j = (k << 6) | lane;                 // lane-consecutive: coalesced
        float4 c = cw[j];
        v2f dx = oxv - c.x;
        v2f dy = oyv - c.y;
        v2f dz = ozv - c.z;
        v2f d2 = dx * dx + dy * dy + dz * dz;    // pk_mul + 2x pk_fma
        #pragma unroll
        for (int q = 0; q < 4; ++q) {
            float4 b4 = bnq[q * N_PTS + j];      // coalesced dwordx4
            v2f p0 = b4.x * d2;                  // pk_mul
            v2f p1 = b4.y * d2;
            v2f p2 = b4.z * d2;
            v2f p3 = b4.w * d2;
            v2f e0 = { exp2_hw(p0.x), exp2_hw(p0.y) };
            v2f e1 = { exp2_hw(p1.x), exp2_hw(p1.y) };
            v2f e2 = { exp2_hw(p2.x), exp2_hw(p2.y) };
            v2f e3 = { exp2_hw(p3.x), exp2_hw(p3.y) };
            acc[q * 4 + 0] += e0 * c.w;          // pk_fma
            acc[q * 4 + 1] += e1 * c.w;
            acc[q * 4 + 2] += e2 * c.w;
            acc[q * 4 + 3] += e3 * c.w;
        }
    }

    // 6-step butterfly over 64 lanes, 16 v2f values
    #pragma unroll
    for (int m = 1; m < 64; m <<= 1) {
        #pragma unroll
        for (int b = 0; b < NBASIS; ++b) {
            v2f other = { __shfl_xor(acc[b].x, m, 64),
                          __shfl_xor(acc[b].y, m, 64) };
            acc[b] += other;
        }
    }

    if (lane == 0) {
        #pragma unroll
        for (int b = 0; b < NBASIS; ++b) {
            float h = hegf[b];                   // wave-uniform s_load
            out[i0 * NBASIS + b] = acc[b].x * h;
            out[i1 * NBASIS + b] = acc[b].y * h;
        }
    }
}

extern "C" void kernel_launch(void* const* d_in, const int* in_sizes, int n_in,
                              void* d_out, int out_size, void* d_ws, size_t ws_size,
                              hipStream_t stream) {
    const float* rho        = (const float*)d_in[0];
    const float* gamma      = (const float*)d_in[1];
    const float* coords     = (const float*)d_in[2];
    const float* weights    = (const float*)d_in[3];
    const float* out_coords = (const float*)d_in[4];
    const float* w1         = (const float*)d_in[5];
    const float* b1         = (const float*)d_in[6];
    const float* w2         = (const float*)d_in[7];
    const float* b2         = (const float*)d_in[8];

    char* ws = (char*)d_ws;
    // ws layout (640 KiB + 64 B):
    //   cw   : N * float4              = 128 KiB  @ 0
    //   bnq  : 4 planes * N * float4   = 512 KiB  @ 128K
    //   hegf : 16 * float                          @ 640K
    float4* cw   = (float4*)(ws);
    float4* bnq  = (float4*)(ws + (128 << 10));
    float*  hegf = (float*) (ws + (640 << 10));

    cg_prep<<<N_PTS / 64, 64, 0, stream>>>(rho, gamma, coords, weights,
                                           w1, b1, w2, b2,
                                           cw, bnq, hegf);

    cg_pairs<<<M_PTS / 8, 256, 0, stream>>>(out_coords, cw, bnq, hegf,
                                            (float*)d_out);
}

// Round 18
// 200.212 us; speedup vs baseline: 1.2322x; 1.0566x over previous
//
#include <hip/hip_runtime.h>
#include <hip/hip_bf16.h>

// CoarseGraining: y[i,b] = heg[b] * sum_j exp(-beta[j,b] * d2(i,j)) * wrho[j]
// N = M = 8192, NB = 16, WIDTH = 32. Inputs float32, output float32.
// R13 (2 i/wave, packed f32, hw v_exp, unroll 2): pairs 134us busy ~104
// (wave64 v_exp ~12-16 issue-cyc -> busy IS the exp floor; ~30us load
// stalls). Failed levers: LDS stage, TLP up (R12/R15), poly exp (R14),
// fusion (R16), unroll 4 (R17: FETCH 2.7->7.1MB, L2 locality loss).
// R18: explicit 1-deep software pipeline — prefetch next iter's 5 loads
// into registers before computing (wrap-indexed, branchless tail), unroll 1.
// Keeps j-window tight (L2-friendly) while covering a full iter of latency.
// Builtins: exp2 = __builtin_amdgcn_exp2f, log2 = __builtin_amdgcn_logf.

#define N_PTS 8192
#define M_PTS 8192
#define NBASIS 16
#define WIDTH 32

typedef float v2f __attribute__((ext_vector_type(2)));

__device__ __forceinline__ float exp2_hw(float x) { return __builtin_amdgcn_exp2f(x); }
__device__ __forceinline__ float log2_hw(float x) { return __builtin_amdgcn_logf(x); }

__device__ __forceinline__ float fast_tanh(float z) {
    float a = fabsf(z);
    float t = __expf(-2.0f * a);
    float r = (1.0f - t) / (1.0f + t);
    return copysignf(r, z);
}

__device__ __forceinline__ float log_cosh_f(float x) {
    float a = fabsf(x);
    return a + __logf(1.0f + __expf(-2.0f * a)) - 0.6931471805599453f;
}

// ---------------- Stage 1: per-source-point quantities ----------------
// cw[j]        = (cx, cy, cz, wrho)
// bnq[q*N + j] = float4{ bn[j][4q..4q+3] }, bn = -log2(e)*beta (q-plane layout)
// hegf[0..15]  = log_cosh(embed(0))^1.5
__global__ __launch_bounds__(64)
void cg_prep(const float* __restrict__ rho,
             const float* __restrict__ gamma,
             const float* __restrict__ coords,
             const float* __restrict__ weights,
             const float* __restrict__ w1,
             const float* __restrict__ b1,
             const float* __restrict__ w2,
             const float* __restrict__ b2,
             float4* __restrict__ cw,
             float4* __restrict__ bnq,
             float* __restrict__ hegf)
{
    const float PI_F = 3.14159265358979323846f;
    const float LOG2E = 1.4426950408889634f;

    __shared__ float s_w1[WIDTH], s_b1[WIDTH], s_w2[WIDTH * NBASIS], s_b2[NBASIS];
    int t = threadIdx.x;
    if (t < WIDTH) { s_w1[t] = w1[t]; s_b1[t] = b1[t]; }
    if (t < NBASIS) s_b2[t] = b2[t];
    #pragma unroll
    for (int k = 0; k < 8; ++k) s_w2[t + 64 * k] = w2[t + 64 * k];
    __syncthreads();

    int j = blockIdx.x * 64 + t;
    {
        float r = rho[j];
        float g = gamma[j];
        const float c83 = 38.28312007948569f;              // 4*(3*pi^2)^(2/3)
        float r83 = exp2_hw(2.6666666667f * log2_hw(r));   // r^(8/3)
        float s2 = g / (c83 * r83);
        float x = __logf(s2 + 1e-4f);

        float emb[NBASIS];
        #pragma unroll
        for (int b = 0; b < NBASIS; ++b) emb[b] = s_b2[b];
        #pragma unroll 4
        for (int w = 0; w < WIDTH; ++w) {
            float h = fast_tanh(fmaf(x, s_w1[w], s_b1[w]));
            #pragma unroll
            for (int b = 0; b < NBASIS; ++b)
                emb[b] = fmaf(h, s_w2[w * NBASIS + b], emb[b]);
        }
        float pref = PI_F * exp2_hw(0.6666666667f * log2_hw(0.5f * r));
        float scale = -LOG2E * pref;
        #pragma unroll
        for (int q = 0; q < 4; ++q) {
            bnq[q * N_PTS + j] = make_float4(scale * log_cosh_f(emb[4 * q + 0]),
                                             scale * log_cosh_f(emb[4 * q + 1]),
                                             scale * log_cosh_f(emb[4 * q + 2]),
                                             scale * log_cosh_f(emb[4 * q + 3]));
        }

        cw[j] = make_float4(coords[j * 3 + 0],
                            coords[j * 3 + 1],
                            coords[j * 3 + 2],
                            weights[j] * r);
    }

    if (blockIdx.x == 0 && t == 0) {
        float emb0[NBASIS];
        #pragma unroll
        for (int b = 0; b < NBASIS; ++b) emb0[b] = s_b2[b];
        for (int w = 0; w < WIDTH; ++w) {
            float h = fast_tanh(s_b1[w]);   // x = 0
            #pragma unroll
            for (int b = 0; b < NBASIS; ++b)
                emb0[b] = fmaf(h, s_w2[w * NBASIS + b], emb0[b]);
        }
        #pragma unroll
        for (int b = 0; b < NBASIS; ++b) {
            float lc = fmaxf(log_cosh_f(emb0[b]), 0.0f);
            hegf[b] = lc * sqrtf(lc);       // lc^1.5
        }
    }
}

// ---------------- Stage 2: all-pairs, 2 i's/wave, sw-pipelined ----------
// wave w owns i0=2w, i1=2w+1; lane L handles j = 64k+L. Packed v2f math.
// 1-deep software pipeline: next iter's cw/bnq loads issue before this
// iter's 32 exps execute; wrap-indexed tail (redundant reads, no branch).
__global__ __launch_bounds__(256, 4)
void cg_pairs(const float* __restrict__ oc,
              const float4* __restrict__ cw,
              const float4* __restrict__ bnq,
              const float* __restrict__ hegf,
              float* __restrict__ out)
{
    int wave = (blockIdx.x << 2) | (threadIdx.x >> 6);
    int lane = threadIdx.x & 63;
    int i0 = wave << 1;
    int i1 = i0 | 1;

    v2f oxv = { oc[i0 * 3 + 0], oc[i1 * 3 + 0] };
    v2f oyv = { oc[i0 * 3 + 1], oc[i1 * 3 + 1] };
    v2f ozv = { oc[i0 * 3 + 2], oc[i1 * 3 + 2] };

    v2f acc[NBASIS];
    #pragma unroll
    for (int b = 0; b < NBASIS; ++b) acc[b] = (v2f)0.0f;

    // pipeline prologue: load k=0
    float4 c  = cw[lane];
    float4 b40 = bnq[0 * N_PTS + lane];
    float4 b41 = bnq[1 * N_PTS + lane];
    float4 b42 = bnq[2 * N_PTS + lane];
    float4 b43 = bnq[3 * N_PTS + lane];

    for (int k = 0; k < N_PTS / 64; ++k) {
        // prefetch k+1 (wraps to k=0 on the last iter: harmless re-read)
        int jn = ((((k + 1) & 127) << 6) | lane);
        float4 cn  = cw[jn];
        float4 n40 = bnq[0 * N_PTS + jn];
        float4 n41 = bnq[1 * N_PTS + jn];
        float4 n42 = bnq[2 * N_PTS + jn];
        float4 n43 = bnq[3 * N_PTS + jn];

        v2f dx = oxv - c.x;
        v2f dy = oyv - c.y;
        v2f dz = ozv - c.z;
        v2f d2 = dx * dx + dy * dy + dz * dz;    // pk_mul + 2x pk_fma

        float4 bq[4] = { b40, b41, b42, b43 };
        #pragma unroll
        for (int q = 0; q < 4; ++q) {
            float4 b4 = bq[q];
            v2f p0 = b4.x * d2;                  // pk_mul
            v2f p1 = b4.y * d2;
            v2f p2 = b4.z * d2;
            v2f p3 = b4.w * d2;
            v2f e0 = { exp2_hw(p0.x), exp2_hw(p0.y) };
            v2f e1 = { exp2_hw(p1.x), exp2_hw(p1.y) };
            v2f e2 = { exp2_hw(p2.x), exp2_hw(p2.y) };
            v2f e3 = { exp2_hw(p3.x), exp2_hw(p3.y) };
            acc[q * 4 + 0] += e0 * c.w;          // pk_fma
            acc[q * 4 + 1] += e1 * c.w;
            acc[q * 4 + 2] += e2 * c.w;
            acc[q * 4 + 3] += e3 * c.w;
        }

        c = cn; b40 = n40; b41 = n41; b42 = n42; b43 = n43;
    }

    // 6-step butterfly over 64 lanes, 16 v2f values
    #pragma unroll
    for (int m = 1; m < 64; m <<= 1) {
        #pragma unroll
        for (int b = 0; b < NBASIS; ++b) {
            v2f other = { __shfl_xor(acc[b].x, m, 64),
                          __shfl_xor(acc[b].y, m, 64) };
            acc[b] += other;
        }
    }

    if (lane == 0) {
        #pragma unroll
        for (int b = 0; b < NBASIS; ++b) {
            float h = hegf[b];                   // wave-uniform s_load
            out[i0 * NBASIS + b] = acc[b].x * h;
            out[i1 * NBASIS + b] = acc[b].y * h;
        }
    }
}

extern "C" void kernel_launch(void* const* d_in, const int* in_sizes, int n_in,
                              void* d_out, int out_size, void* d_ws, size_t ws_size,
                              hipStream_t stream) {
    const float* rho        = (const float*)d_in[0];
    const float* gamma      = (const float*)d_in[1];
    const float* coords     = (const float*)d_in[2];
    const float* weights    = (const float*)d_in[3];
    const float* out_coords = (const float*)d_in[4];
    const float* w1         = (const float*)d_in[5];
    const float* b1         = (const float*)d_in[6];
    const float* w2         = (const float*)d_in[7];
    const float* b2         = (const float*)d_in[8];

    char* ws = (char*)d_ws;
    // ws layout (640 KiB + 64 B):
    //   cw   : N * float4              = 128 KiB  @ 0
    //   bnq  : 4 planes * N * float4   = 512 KiB  @ 128K
    //   hegf : 16 * float                          @ 640K
    float4* cw   = (float4*)(ws);
    float4* bnq  = (float4*)(ws + (128 << 10));
    float*  hegf = (float*) (ws + (640 << 10));

    cg_prep<<<N_PTS / 64, 64, 0, stream>>>(rho, gamma, coords, weights,
                                           w1, b1, w2, b2,
                                           cw, bnq, hegf);

    cg_pairs<<<M_PTS / 8, 256, 0, stream>>>(out_coords, cw, bnq, hegf,
                                            (float*)d_out);
}